// Round 1
// baseline (151.012 us; speedup 1.0000x reference)
//
#include <hip/hip_runtime.h>
#include <math.h>

#define B_SZ 64
#define SEQ 2048
#define DM 12
#define DI 24
#define DS 16
#define DC 4
#define DTR 4
#define NSEG 16
#define SEGLEN (SEQ / NSEG) /* 128 */

// Workspace layout:
//  W   : [B][SEQ][64] floats  — per (b,t): [0..23]=xc, [24..47]=dt, [48..63]=B
//  segA: [B][NSEG][DI*DS]
//  segB: [B][NSEG][DI*DS]

__device__ __forceinline__ float silu_f(float v) {
    return v / (1.f + __expf(-v));
}

__global__ __launch_bounds__(256) void prep_kernel(
    const float* __restrict__ x, const float* __restrict__ ipw,
    const float* __restrict__ cw, const float* __restrict__ cb,
    const float* __restrict__ xpw, const float* __restrict__ dpw,
    const float* __restrict__ dpb, float* __restrict__ W)
{
    int idx = blockIdx.x * blockDim.x + threadIdx.x;   // b*SEQ + t
    if (idx >= B_SZ * SEQ) return;
    int b = idx / SEQ, t = idx % SEQ;
    const float* xb = x + (size_t)b * SEQ * DM;

    // load the 4 input rows (causal window, zero-padded)
    float xv[DC][DM];
#pragma unroll
    for (int k = 0; k < DC; ++k) {
        int tt = t - (DC - 1) + k;
#pragma unroll
        for (int m = 0; m < DM; ++m)
            xv[k][m] = (tt >= 0) ? xb[tt * DM + m] : 0.f;
    }

    // in_proj (ssm half) + depthwise causal conv + silu
    float xc[DI];
#pragma unroll
    for (int d = 0; d < DI; ++d) {
        float acc = cb[d];
#pragma unroll
        for (int k = 0; k < DC; ++k) {
            float xin = 0.f;
#pragma unroll
            for (int m = 0; m < DM; ++m) xin += xv[k][m] * ipw[d * DM + m];
            acc += xin * cw[d * DC + k];
        }
        xc[d] = silu_f(acc);
    }

    float* wp = W + (size_t)idx * 64;

    // x_proj: dt_raw (rows 0..3) and B (rows 4..19)
    float dtr[DTR];
#pragma unroll
    for (int r = 0; r < DTR; ++r) {
        float s = 0.f;
#pragma unroll
        for (int d = 0; d < DI; ++d) s += xc[d] * xpw[r * DI + d];
        dtr[r] = s;
    }
#pragma unroll
    for (int j = 0; j < DS; ++j) {
        float s = 0.f;
#pragma unroll
        for (int d = 0; d < DI; ++d) s += xc[d] * xpw[(DTR + j) * DI + d];
        wp[48 + j] = s;
    }

    // dt = softplus(dt_raw @ dt_proj_w^T + b)
#pragma unroll
    for (int d = 0; d < DI; ++d) {
        float s = dpb[d];
#pragma unroll
        for (int r = 0; r < DTR; ++r) s += dtr[r] * dpw[d * DTR + r];
        float sp = fmaxf(s, 0.f) + log1pf(__expf(-fabsf(s)));
        wp[DI + d] = sp;
        wp[d] = xc[d];
    }
}

// Each block: one (batch, segment). Thread = d*16+s state element.
// Computes affine segment reduction: h_out = a_acc * h_in + b_acc.
__global__ __launch_bounds__(384) void scan_seg_kernel(
    const float* __restrict__ W, const float* __restrict__ A_log,
    float* __restrict__ segA, float* __restrict__ segB)
{
    int b = blockIdx.x / NSEG, seg = blockIdx.x % NSEG;
    int tid = threadIdx.x;             // d*DS + s
    int d = tid >> 4, s = tid & 15;
    float Aval = -expf(A_log[tid]);    // A_log is [DI][DS] row-major

    const float* p = W + ((size_t)b * SEQ + (size_t)seg * SEGLEN) * 64;
    float a_acc = 1.f, b_acc = 0.f;
    for (int i = 0; i < SEGLEN; ++i, p += 64) {
        float xcv = p[d];
        float dt  = p[DI + d];
        float Bv  = p[48 + s];
        float a = __expf(dt * Aval);
        b_acc = fmaf(a, b_acc, dt * Bv * xcv);
        a_acc *= a;
    }
    size_t o = (size_t)blockIdx.x * (DI * DS) + tid;
    segA[o] = a_acc;
    segB[o] = b_acc;
}

// One block per batch: combine segments sequentially, then epilogue.
__global__ __launch_bounds__(384) void finish_kernel(
    const float* __restrict__ segA, const float* __restrict__ segB,
    const float* __restrict__ W, const float* __restrict__ x,
    const float* __restrict__ ipw, const float* __restrict__ xpw,
    const float* __restrict__ Dv, const float* __restrict__ opw,
    const float* __restrict__ fcw, const float* __restrict__ fcb,
    float* __restrict__ out)
{
    int b = blockIdx.x;
    int tid = threadIdx.x;

    float h = 0.f;
#pragma unroll
    for (int g = 0; g < NSEG; ++g) {
        size_t o = ((size_t)(b * NSEG + g)) * (DI * DS) + tid;
        h = fmaf(segA[o], h, segB[o]);
    }

    __shared__ float h_sh[DI * DS];
    __shared__ float xcl[DI], CL[DS], zv[DI], yv[DI], ov[DM];
    h_sh[tid] = h;
    if (tid < DI) xcl[tid] = W[((size_t)b * SEQ + SEQ - 1) * 64 + tid];
    __syncthreads();

    // C at last timestep: x_proj rows 20..35 applied to xc_last
    if (tid < DS) {
        float s = 0.f;
#pragma unroll
        for (int d = 0; d < DI; ++d) s += xcl[d] * xpw[(DTR + DS + tid) * DI + d];
        CL[tid] = s;
    }
    // z at last timestep: in_proj rows 24..47 applied to x_last
    if (tid < DI) {
        const float* xr = x + ((size_t)b * SEQ + SEQ - 1) * DM;
        float s = 0.f;
#pragma unroll
        for (int m = 0; m < DM; ++m) s += xr[m] * ipw[(DI + tid) * DM + m];
        zv[tid] = s;
    }
    __syncthreads();

    if (tid < DI) {
        float y = 0.f;
#pragma unroll
        for (int j = 0; j < DS; ++j) y += h_sh[tid * DS + j] * CL[j];
        y += xcl[tid] * Dv[tid];
        float z = zv[tid];
        y *= silu_f(z);
        yv[tid] = y;
    }
    __syncthreads();

    if (tid < DM) {
        float s = 0.f;
#pragma unroll
        for (int d = 0; d < DI; ++d) s += yv[d] * opw[tid * DI + d];
        ov[tid] = s;
    }
    __syncthreads();

    if (tid == 0) {
        float s = fcb[0];
#pragma unroll
        for (int e = 0; e < DM; ++e) s += ov[e] * fcw[e];
        out[b] = s;
    }
}

extern "C" void kernel_launch(void* const* d_in, const int* in_sizes, int n_in,
                              void* d_out, int out_size, void* d_ws, size_t ws_size,
                              hipStream_t stream)
{
    const float* x   = (const float*)d_in[0];
    const float* ipw = (const float*)d_in[1];
    const float* cw  = (const float*)d_in[2];
    const float* cb  = (const float*)d_in[3];
    const float* xpw = (const float*)d_in[4];
    const float* dpw = (const float*)d_in[5];
    const float* dpb = (const float*)d_in[6];
    const float* Al  = (const float*)d_in[7];
    const float* Dv  = (const float*)d_in[8];
    const float* opw = (const float*)d_in[9];
    const float* fcw = (const float*)d_in[10];
    const float* fcb = (const float*)d_in[11];

    float* W    = (float*)d_ws;                                   // B*SEQ*64
    float* segA = W + (size_t)B_SZ * SEQ * 64;                    // B*NSEG*384
    float* segB = segA + (size_t)B_SZ * NSEG * DI * DS;

    prep_kernel<<<(B_SZ * SEQ + 255) / 256, 256, 0, stream>>>(
        x, ipw, cw, cb, xpw, dpw, dpb, W);
    scan_seg_kernel<<<B_SZ * NSEG, 384, 0, stream>>>(W, Al, segA, segB);
    finish_kernel<<<B_SZ, 384, 0, stream>>>(
        segA, segB, W, x, ipw, xpw, Dv, opw, fcw, fcb, (float*)d_out);
}

// Round 2
// 144.634 us; speedup vs baseline: 1.0441x; 1.0441x over previous
//
#include <hip/hip_runtime.h>
#include <math.h>

#define B_SZ 64
#define SEQ 2048
#define DM 12
#define DI 24
#define DS 16
#define DC 4
#define DTR 4
#define NSEG 16
#define SEGLEN 128
#define LPAD 132   /* SEGLEN + 4: breaks 512B-row bank aliasing, keeps 16B align */

__device__ __forceinline__ float silu_f(float v) { return v / (1.f + __expf(-v)); }
__device__ __forceinline__ float softplus_f(float v) {
    return fmaxf(v, 0.f) + __logf(1.f + __expf(-fabsf(v)));
}

// One block per (batch, segment). Phases:
//   A: conv+silu -> xc (LDS), 3 threads/t each owning 8 channels
//   B: x_proj -> dt_raw, B (LDS)
//   C: dt softplus; overwrite xc slot with du = dt*xc
//   scan: 384 (d,s) threads, affine segment reduction from LDS float4 streams
__global__ __launch_bounds__(384) void fused_scan_kernel(
    const float* __restrict__ x, const float* __restrict__ ipw,
    const float* __restrict__ cw, const float* __restrict__ cb,
    const float* __restrict__ xpw, const float* __restrict__ dpw,
    const float* __restrict__ dpb, const float* __restrict__ A_log,
    float* __restrict__ segA, float* __restrict__ segB)
{
    __shared__ __align__(16) float xcdu_s[DI][LPAD]; // xc in A/B, du=dt*xc after C
    __shared__ __align__(16) float dts[DI][LPAD];
    __shared__ __align__(16) float Bs[DS][LPAD];
    __shared__ __align__(16) float dtr_s[DTR][LPAD];

    const int tid = threadIdx.x;
    const int b = blockIdx.x >> 4, seg = blockIdx.x & 15;
    const int t0 = seg * SEGLEN;

    const float Aval = -__expf(A_log[tid]);   // tid = d*16+s, row-major [DI][DS]

    const int j = tid >> 7;      // 0..2 : channel-group owner
    const int t = tid & 127;     // local timestep

    // ---- Phase A: in_proj + causal depthwise conv + silu for d in [8j,8j+8) ----
    float xc_loc[8];
    {
        float acc[8];
#pragma unroll
        for (int i = 0; i < 8; ++i) acc[i] = cb[j * 8 + i];
#pragma unroll
        for (int k = 0; k < DC; ++k) {
            int gt = t0 + t - (DC - 1) + k;
            float4 r0, r1, r2;
            if (gt >= 0) {
                const float4* xp = (const float4*)(x + ((size_t)b * SEQ + gt) * DM);
                r0 = xp[0]; r1 = xp[1]; r2 = xp[2];
            } else {
                r0 = make_float4(0.f, 0.f, 0.f, 0.f); r1 = r0; r2 = r0;
            }
            float row[12] = {r0.x, r0.y, r0.z, r0.w, r1.x, r1.y, r1.z, r1.w,
                             r2.x, r2.y, r2.z, r2.w};
#pragma unroll
            for (int i = 0; i < 8; ++i) {
                int d = j * 8 + i;
                float xin = 0.f;
#pragma unroll
                for (int m = 0; m < DM; ++m) xin = fmaf(row[m], ipw[d * DM + m], xin);
                acc[i] = fmaf(xin, cw[d * DC + k], acc[i]);
            }
        }
#pragma unroll
        for (int i = 0; i < 8; ++i) {
            float v = silu_f(acc[i]);
            xc_loc[i] = v;
            xcdu_s[j * 8 + i][t] = v;
        }
    }
    __syncthreads();

    // ---- Phase B: x_proj rows (dt_raw: 0..3, B: 4..19), row-strided over j ----
    {
        float xc[DI];
#pragma unroll
        for (int d = 0; d < DI; ++d) xc[d] = xcdu_s[d][t];
        for (int r = j; r < DTR + DS; r += 3) {
            float s = 0.f;
#pragma unroll
            for (int d = 0; d < DI; ++d) s = fmaf(xc[d], xpw[r * DI + d], s);
            if (r < DTR) dtr_s[r][t] = s;
            else         Bs[r - DTR][t] = s;
        }
    }
    __syncthreads();

    // ---- Phase C: dt = softplus(dt_raw @ dpw^T + dpb); du = dt*xc ----
    {
        float dtr[DTR];
#pragma unroll
        for (int r = 0; r < DTR; ++r) dtr[r] = dtr_s[r][t];
#pragma unroll
        for (int i = 0; i < 8; ++i) {
            int d = j * 8 + i;
            float s = dpb[d];
#pragma unroll
            for (int r = 0; r < DTR; ++r) s = fmaf(dtr[r], dpw[d * DTR + r], s);
            float dt = softplus_f(s);
            dts[d][t] = dt;
            xcdu_s[d][t] = dt * xc_loc[i];   // du
        }
    }
    __syncthreads();

    // ---- Scan: h_t = exp(dt*A)*h + du*B, reduced to (a_acc, b_acc) ----
    {
        const int d = tid >> 4, s = tid & 15;
        float a_acc = 1.f, b_acc = 0.f;
        const float4* dtp = (const float4*)&dts[d][0];
        const float4* dup = (const float4*)&xcdu_s[d][0];
        const float4* Bp  = (const float4*)&Bs[s][0];
#pragma unroll 4
        for (int i = 0; i < SEGLEN / 4; ++i) {
            float4 dt4 = dtp[i], du4 = dup[i], B4 = Bp[i];
            float a;
            a = __expf(dt4.x * Aval); b_acc = fmaf(a, b_acc, du4.x * B4.x); a_acc *= a;
            a = __expf(dt4.y * Aval); b_acc = fmaf(a, b_acc, du4.y * B4.y); a_acc *= a;
            a = __expf(dt4.z * Aval); b_acc = fmaf(a, b_acc, du4.z * B4.z); a_acc *= a;
            a = __expf(dt4.w * Aval); b_acc = fmaf(a, b_acc, du4.w * B4.w); a_acc *= a;
        }
        size_t o = (size_t)blockIdx.x * (DI * DS) + tid;
        segA[o] = a_acc;
        segB[o] = b_acc;
    }
}

// One block per batch: combine 16 segments, then the tiny epilogue.
__global__ __launch_bounds__(384) void finish_kernel(
    const float* __restrict__ segA, const float* __restrict__ segB,
    const float* __restrict__ x, const float* __restrict__ ipw,
    const float* __restrict__ cw, const float* __restrict__ cb,
    const float* __restrict__ xpw, const float* __restrict__ Dv,
    const float* __restrict__ opw, const float* __restrict__ fcw,
    const float* __restrict__ fcb, float* __restrict__ out)
{
    int b = blockIdx.x, tid = threadIdx.x;

    float h = 0.f;
#pragma unroll
    for (int g = 0; g < NSEG; ++g) {
        size_t o = ((size_t)(b * NSEG + g)) * (DI * DS) + tid;
        h = fmaf(segA[o], h, segB[o]);
    }

    __shared__ float h_sh[DI * DS];
    __shared__ float xcl[DI], CL[DS], zv[DI], yv[DI], ov[DM];
    h_sh[tid] = h;

    const float* xr = x + ((size_t)b * SEQ + SEQ - 1) * DM;
    if (tid < DI) {
        // recompute xc at last timestep (conv window rows SEQ-4..SEQ-1)
        float acc = cb[tid];
#pragma unroll
        for (int k = 0; k < DC; ++k) {
            const float* row = x + ((size_t)b * SEQ + (SEQ - DC + k)) * DM;
            float xin = 0.f;
#pragma unroll
            for (int m = 0; m < DM; ++m) xin = fmaf(row[m], ipw[tid * DM + m], xin);
            acc = fmaf(xin, cw[tid * DC + k], acc);
        }
        xcl[tid] = silu_f(acc);
        // z at last timestep: in_proj rows 24..47
        float s = 0.f;
#pragma unroll
        for (int m = 0; m < DM; ++m) s = fmaf(xr[m], ipw[(DI + tid) * DM + m], s);
        zv[tid] = s;
    }
    __syncthreads();

    if (tid < DS) {
        float s = 0.f;
#pragma unroll
        for (int d = 0; d < DI; ++d) s = fmaf(xcl[d], xpw[(DTR + DS + tid) * DI + d], s);
        CL[tid] = s;
    }
    __syncthreads();

    if (tid < DI) {
        float y = 0.f;
#pragma unroll
        for (int s2 = 0; s2 < DS; ++s2) y = fmaf(h_sh[tid * DS + s2], CL[s2], y);
        y = fmaf(xcl[tid], Dv[tid], y);
        yv[tid] = y * silu_f(zv[tid]);
    }
    __syncthreads();

    if (tid < DM) {
        float s = 0.f;
#pragma unroll
        for (int d = 0; d < DI; ++d) s = fmaf(yv[d], opw[tid * DI + d], s);
        ov[tid] = s;
    }
    __syncthreads();

    if (tid == 0) {
        float s = fcb[0];
#pragma unroll
        for (int e = 0; e < DM; ++e) s = fmaf(ov[e], fcw[e], s);
        out[b] = s;
    }
}

extern "C" void kernel_launch(void* const* d_in, const int* in_sizes, int n_in,
                              void* d_out, int out_size, void* d_ws, size_t ws_size,
                              hipStream_t stream)
{
    const float* x   = (const float*)d_in[0];
    const float* ipw = (const float*)d_in[1];
    const float* cw  = (const float*)d_in[2];
    const float* cb  = (const float*)d_in[3];
    const float* xpw = (const float*)d_in[4];
    const float* dpw = (const float*)d_in[5];
    const float* dpb = (const float*)d_in[6];
    const float* Al  = (const float*)d_in[7];
    const float* Dv  = (const float*)d_in[8];
    const float* opw = (const float*)d_in[9];
    const float* fcw = (const float*)d_in[10];
    const float* fcb = (const float*)d_in[11];

    float* segA = (float*)d_ws;                            // [B*NSEG][384]
    float* segB = segA + (size_t)B_SZ * NSEG * DI * DS;

    fused_scan_kernel<<<B_SZ * NSEG, 384, 0, stream>>>(
        x, ipw, cw, cb, xpw, dpw, dpb, Al, segA, segB);
    finish_kernel<<<B_SZ, 384, 0, stream>>>(
        segA, segB, x, ipw, cw, cb, xpw, Dv, opw, fcw, fcb, (float*)d_out);
}

// Round 3
// 117.217 us; speedup vs baseline: 1.2883x; 1.2339x over previous
//
#include <hip/hip_runtime.h>
#include <math.h>

#define B_SZ 64
#define SEQ 2048
#define DM 12
#define DI 24
#define DS 16
#define DC 4
#define DTR 4
#define NSEG 32
#define SEGLEN 64
#define LP 68   /* SEGLEN + 4 pad: row = 272 B = 17x16 B -> float4-aligned rows */

__device__ __forceinline__ float silu_f(float v) { return v / (1.f + __expf(-v)); }
__device__ __forceinline__ float softplus_f(float v) {
    return fmaxf(v, 0.f) + __logf(1.f + __expf(-fabsf(v)));
}
__device__ __forceinline__ float dot12(const float4 w[3], float4 r0, float4 r1, float4 r2) {
    float s = 0.f;
    s = fmaf(w[0].x, r0.x, s); s = fmaf(w[0].y, r0.y, s);
    s = fmaf(w[0].z, r0.z, s); s = fmaf(w[0].w, r0.w, s);
    s = fmaf(w[1].x, r1.x, s); s = fmaf(w[1].y, r1.y, s);
    s = fmaf(w[1].z, r1.z, s); s = fmaf(w[1].w, r1.w, s);
    s = fmaf(w[2].x, r2.x, s); s = fmaf(w[2].y, r2.y, s);
    s = fmaf(w[2].z, r2.z, s); s = fmaf(w[2].w, r2.w, s);
    return s;
}

// One block per (batch, segment). 384 threads.
// Phases A-C: thread = (j = tid>>6 in [0,6), t = tid&63); thread owns channels 4j..4j+3.
// Scan: thread = (d = tid>>4, s = tid&15).
__global__ __launch_bounds__(384) void fused_scan_kernel(
    const float* __restrict__ x, const float* __restrict__ ipw,
    const float* __restrict__ cw, const float* __restrict__ cb,
    const float* __restrict__ xpw, const float* __restrict__ dpw,
    const float* __restrict__ dpb, const float* __restrict__ A_log,
    float* __restrict__ segA, float* __restrict__ segB)
{
    __shared__ __align__(16) float xc_s[DI][LP];   // xc in A/B, du after C
    __shared__ __align__(16) float dts[DI][LP];
    __shared__ __align__(16) float Bs[DS][LP];
    __shared__ __align__(16) float dtr_s[DTR][LP];

    const int tid = threadIdx.x;
    const int b = blockIdx.x >> 5, seg = blockIdx.x & 31;
    const int t0 = seg * SEGLEN;
    const int j = tid >> 6;       // wave index 0..5
    const int t = tid & 63;
    const int d0 = j * 4;

    const float Aval = -__expf(A_log[tid]);  // for scan phase (tid = d*16+s)

    // ---- Phase A: in_proj + causal conv + silu, 4 channels/thread ----
    float xc_loc[4];
    {
        float4 wA[4][3];
        float cwr[4][4];
        float acc[4];
#pragma unroll
        for (int i = 0; i < 4; ++i) {
            const float4* wp = (const float4*)(ipw + (d0 + i) * DM);
            wA[i][0] = wp[0]; wA[i][1] = wp[1]; wA[i][2] = wp[2];
            const float4 cw4 = *(const float4*)(cw + (d0 + i) * DC);
            cwr[i][0] = cw4.x; cwr[i][1] = cw4.y; cwr[i][2] = cw4.z; cwr[i][3] = cw4.w;
            acc[i] = cb[d0 + i];
        }
#pragma unroll
        for (int k = 0; k < DC; ++k) {
            int gt = t0 + t - (DC - 1) + k;
            float4 r0, r1, r2;
            if (gt >= 0) {
                const float4* xp = (const float4*)(x + ((size_t)b * SEQ + gt) * DM);
                r0 = xp[0]; r1 = xp[1]; r2 = xp[2];
            } else {
                r0 = make_float4(0.f, 0.f, 0.f, 0.f); r1 = r0; r2 = r0;
            }
#pragma unroll
            for (int i = 0; i < 4; ++i) {
                float xin = dot12(wA[i], r0, r1, r2);
                acc[i] = fmaf(xin, cwr[i][k], acc[i]);
            }
        }
#pragma unroll
        for (int i = 0; i < 4; ++i) {
            float v = silu_f(acc[i]);
            xc_loc[i] = v;
            xc_s[d0 + i][t] = v;
        }
    }
    __syncthreads();

    // ---- Phase B: x_proj rows r == j (mod 6); rows 0..3 -> dt_raw, 4..19 -> B ----
    {
        float xc[DI];
#pragma unroll
        for (int d = 0; d < DI; ++d) xc[d] = xc_s[d][t];
        for (int r = j; r < DTR + DS; r += 6) {
            const float4* wr = (const float4*)(xpw + r * DI);
            float4 w4[6];
#pragma unroll
            for (int c = 0; c < 6; ++c) w4[c] = wr[c];
            float s = 0.f;
#pragma unroll
            for (int c = 0; c < 6; ++c) {
                s = fmaf(w4[c].x, xc[4 * c + 0], s);
                s = fmaf(w4[c].y, xc[4 * c + 1], s);
                s = fmaf(w4[c].z, xc[4 * c + 2], s);
                s = fmaf(w4[c].w, xc[4 * c + 3], s);
            }
            if (r < DTR) dtr_s[r][t] = s;
            else         Bs[r - DTR][t] = s;
        }
    }
    __syncthreads();

    // ---- Phase C: dt = softplus(dt_raw @ dpw^T + dpb); du = dt*xc ----
    {
        float dtr[DTR];
#pragma unroll
        for (int r = 0; r < DTR; ++r) dtr[r] = dtr_s[r][t];
#pragma unroll
        for (int i = 0; i < 4; ++i) {
            int d = d0 + i;
            const float4 w4 = *(const float4*)(dpw + d * DTR);
            float s = dpb[d];
            s = fmaf(dtr[0], w4.x, s); s = fmaf(dtr[1], w4.y, s);
            s = fmaf(dtr[2], w4.z, s); s = fmaf(dtr[3], w4.w, s);
            float dt = softplus_f(s);
            dts[d][t] = dt;
            xc_s[d][t] = dt * xc_loc[i];   // du
        }
    }
    __syncthreads();

    // ---- Scan: affine segment reduction over 64 steps ----
    {
        const int d = tid >> 4, s = tid & 15;
        float a_acc = 1.f, b_acc = 0.f;
        const float4* dtp = (const float4*)&dts[d][0];
        const float4* dup = (const float4*)&xc_s[d][0];
        const float4* Bp  = (const float4*)&Bs[s][0];
#pragma unroll 4
        for (int i = 0; i < SEGLEN / 4; ++i) {
            float4 dt4 = dtp[i], du4 = dup[i], B4 = Bp[i];
            float a;
            a = __expf(dt4.x * Aval); b_acc = fmaf(a, b_acc, du4.x * B4.x); a_acc *= a;
            a = __expf(dt4.y * Aval); b_acc = fmaf(a, b_acc, du4.y * B4.y); a_acc *= a;
            a = __expf(dt4.z * Aval); b_acc = fmaf(a, b_acc, du4.z * B4.z); a_acc *= a;
            a = __expf(dt4.w * Aval); b_acc = fmaf(a, b_acc, du4.w * B4.w); a_acc *= a;
        }
        size_t o = (size_t)blockIdx.x * (DI * DS) + tid;
        segA[o] = a_acc;
        segB[o] = b_acc;
    }
}

// One block per batch: combine 32 segments, then the tiny epilogue.
__global__ __launch_bounds__(384) void finish_kernel(
    const float* __restrict__ segA, const float* __restrict__ segB,
    const float* __restrict__ x, const float* __restrict__ ipw,
    const float* __restrict__ cw, const float* __restrict__ cb,
    const float* __restrict__ xpw, const float* __restrict__ Dv,
    const float* __restrict__ opw, const float* __restrict__ fcw,
    const float* __restrict__ fcb, float* __restrict__ out)
{
    int b = blockIdx.x, tid = threadIdx.x;

    float h = 0.f;
#pragma unroll
    for (int g = 0; g < NSEG; ++g) {
        size_t o = ((size_t)(b * NSEG + g)) * (DI * DS) + tid;
        h = fmaf(segA[o], h, segB[o]);
    }

    __shared__ float h_sh[DI * DS];
    __shared__ float xcl[DI], CL[DS], zv[DI], yv[DI], ov[DM];
    h_sh[tid] = h;

    const float* xr = x + ((size_t)b * SEQ + SEQ - 1) * DM;
    if (tid < DI) {
        float acc = cb[tid];
#pragma unroll
        for (int k = 0; k < DC; ++k) {
            const float* row = x + ((size_t)b * SEQ + (SEQ - DC + k)) * DM;
            float xin = 0.f;
#pragma unroll
            for (int m = 0; m < DM; ++m) xin = fmaf(row[m], ipw[tid * DM + m], xin);
            acc = fmaf(xin, cw[tid * DC + k], acc);
        }
        xcl[tid] = silu_f(acc);
        float s = 0.f;
#pragma unroll
        for (int m = 0; m < DM; ++m) s = fmaf(xr[m], ipw[(DI + tid) * DM + m], s);
        zv[tid] = s;
    }
    __syncthreads();

    if (tid < DS) {
        float s = 0.f;
#pragma unroll
        for (int d = 0; d < DI; ++d) s = fmaf(xcl[d], xpw[(DTR + DS + tid) * DI + d], s);
        CL[tid] = s;
    }
    __syncthreads();

    if (tid < DI) {
        float y = 0.f;
#pragma unroll
        for (int s2 = 0; s2 < DS; ++s2) y = fmaf(h_sh[tid * DS + s2], CL[s2], y);
        y = fmaf(xcl[tid], Dv[tid], y);
        yv[tid] = y * silu_f(zv[tid]);
    }
    __syncthreads();

    if (tid < DM) {
        float s = 0.f;
#pragma unroll
        for (int d = 0; d < DI; ++d) s = fmaf(yv[d], opw[tid * DI + d], s);
        ov[tid] = s;
    }
    __syncthreads();

    if (tid == 0) {
        float s = fcb[0];
#pragma unroll
        for (int e = 0; e < DM; ++e) s = fmaf(ov[e], fcw[e], s);
        out[b] = s;
    }
}

extern "C" void kernel_launch(void* const* d_in, const int* in_sizes, int n_in,
                              void* d_out, int out_size, void* d_ws, size_t ws_size,
                              hipStream_t stream)
{
    const float* x   = (const float*)d_in[0];
    const float* ipw = (const float*)d_in[1];
    const float* cw  = (const float*)d_in[2];
    const float* cb  = (const float*)d_in[3];
    const float* xpw = (const float*)d_in[4];
    const float* dpw = (const float*)d_in[5];
    const float* dpb = (const float*)d_in[6];
    const float* Al  = (const float*)d_in[7];
    const float* Dv  = (const float*)d_in[8];
    const float* opw = (const float*)d_in[9];
    const float* fcw = (const float*)d_in[10];
    const float* fcb = (const float*)d_in[11];

    float* segA = (float*)d_ws;                            // [B*NSEG][384]
    float* segB = segA + (size_t)B_SZ * NSEG * DI * DS;

    fused_scan_kernel<<<B_SZ * NSEG, 384, 0, stream>>>(
        x, ipw, cw, cb, xpw, dpw, dpb, Al, segA, segB);
    finish_kernel<<<B_SZ, 384, 0, stream>>>(
        segA, segB, x, ipw, cw, cb, xpw, Dv, opw, fcw, fcb, (float*)d_out);
}